// Round 10
// baseline (207.187 us; speedup 1.0000x reference)
//
#include <hip/hip_runtime.h>
#include <math.h>

#define BB 4
#define NN 1024
#define MM 1024
#define HH 64
#define NT 8              // n-tiles
#define BN 128            // n per block
#define BM 64             // m per block
#define MT (MM / BM)      // 16 m-tiles

// measurement-round amplification (arithmetic-neutral)
#define REPS_PREP 32
#define REPS_FUSED 4
#define REPS_COMB 64

static constexpr float NEG_BIG = -3.0e38f;
static constexpr float SCALE = -0.72134752044448170f;   // -0.5 * log2(e)

__device__ __forceinline__ int opaque_zero() {
    int z;
    asm volatile("s_mov_b32 %0, 0" : "=s"(z));
    return z;
}

__device__ __forceinline__ void gload16(const void* gsrc, void* lds_base) {
    __builtin_amdgcn_global_load_lds(
        (const __attribute__((address_space(1))) void*)gsrc,
        (__attribute__((address_space(3))) void*)lds_base,
        16, 0, 0);
}

// ---------------- Kernel 1: prep (K-MLP, Q-MLP, vhat = V.Wo), fine-grained ----------------
__global__ __launch_bounds__(256)
void prep_kernel(const float* __restrict__ coords_f,
                 const float* __restrict__ values_f,
                 const float* __restrict__ coords_t,
                 const float* __restrict__ Wk1, const float* __restrict__ bk1,
                 const float* __restrict__ Wk2, const float* __restrict__ bk2,
                 const float* __restrict__ Wq1, const float* __restrict__ bq1,
                 const float* __restrict__ Wq2, const float* __restrict__ bq2,
                 const float* __restrict__ Wv1, const float* __restrict__ bv1,
                 const float* __restrict__ Wv2, const float* __restrict__ bv2,
                 const float* __restrict__ Wo,
                 float* __restrict__ Kout, float* __restrict__ Qout,
                 float* __restrict__ vhat,
                 int reps, float inv_reps) {
    const int bx = blockIdx.x;
    const int tid = threadIdx.x;

    if (bx < 512) {
        const int type = bx >> 8;                 // 0 = K, 1 = Q
        const int sub = bx & 255;
        const int row = (sub >> 4) * 256 + tid;   // 0..4095
        const int co  = (sub & 15) * 4;           // 4-output chunk

        const float* in = type ? coords_t : coords_f;
        const float* W1 = type ? Wq1 : Wk1;
        const float* b1 = type ? bq1 : bk1;
        const float* W2 = type ? Wq2 : Wk2;
        const float* b2 = type ? bq2 : bk2;
        float* out = type ? Qout : Kout;

        const float in0 = in[row * 3 + 0];
        const float in1 = in[row * 3 + 1];
        const float in2 = in[row * 3 + 2];

        float acc[4];
#pragma unroll
        for (int j = 0; j < 4; ++j) acc[j] = 0.0f;

        for (int rep = 0; rep < reps; ++rep) {
            const int zz = opaque_zero();
            const float* W1r = W1 + zz;
            const float* b1r = b1 + zz;
            const float* W2r = W2 + zz;
#pragma unroll 4
            for (int hi = 0; hi < HH; ++hi) {
                float h = b1r[hi];
                h = fmaf(in0, W1r[hi], h);
                h = fmaf(in1, W1r[64 + hi], h);
                h = fmaf(in2, W1r[128 + hi], h);
                h = fmaxf(h, 0.0f);
                const float* w = W2r + hi * 64 + co;
#pragma unroll
                for (int j = 0; j < 4; ++j) acc[j] = fmaf(h, w[j], acc[j]);
            }
        }
        float4* o = reinterpret_cast<float4*>(out + row * 64 + co);
        *o = make_float4(acc[0] * inv_reps + b2[co + 0],
                         acc[1] * inv_reps + b2[co + 1],
                         acc[2] * inv_reps + b2[co + 2],
                         acc[3] * inv_reps + b2[co + 3]);
    } else {
        const int sub = bx - 512;                 // 0..15
        __shared__ float w2o[64];
        __shared__ float b2o_sh;
        if (tid < 64) {
            float s = 0.0f;
            for (int ho = 0; ho < 64; ++ho) s = fmaf(Wv2[tid * 64 + ho], Wo[ho], s);
            w2o[tid] = s;
        }
        if (tid == 0) {
            float s = 0.0f;
            for (int ho = 0; ho < 64; ++ho) s = fmaf(bv2[ho], Wo[ho], s);
            b2o_sh = s;
        }
        __syncthreads();

        const int row = sub * 256 + tid;
        const float* vin = values_f + row * 5;
        const float i0 = vin[0], i1 = vin[1], i2 = vin[2], i3 = vin[3], i4 = vin[4];

        float sacc = 0.0f;
        for (int rep = 0; rep < reps; ++rep) {
            const int zz = opaque_zero();
            const float* Wv1r = Wv1 + zz;
            const float* bv1r = bv1 + zz;
            for (int j = 0; j < HH; ++j) {
                float h = bv1r[j];
                h = fmaf(i0, Wv1r[j], h);
                h = fmaf(i1, Wv1r[64 + j], h);
                h = fmaf(i2, Wv1r[128 + j], h);
                h = fmaf(i3, Wv1r[192 + j], h);
                h = fmaf(i4, Wv1r[256 + j], h);
                h = fmaxf(h, 0.0f);
                sacc = fmaf(h, w2o[j], sacc);
            }
        }
        vhat[row] = sacc * inv_reps + b2o_sh;
    }
}

// ---------------- Kernel 2: GEMM-tiled L1-dist + in-block softmax partials ----------------
// R9 structure (gload_lds staging, 60 KB LDS, 2 blocks/CU) + rep amplification of
// the dist loop only (LDS reads + VALU — the part under investigation).
__global__ __launch_bounds__(256, 2)
void fused_kernel(const float* __restrict__ Kb,
                  const float* __restrict__ Qb,
                  const float* __restrict__ vh,
                  float* __restrict__ mxp,
                  float* __restrict__ denp,
                  float* __restrict__ nump,
                  int reps, float inv_reps) {
    __shared__ float kt[BN * 64];        // 32 KB swizzled K tile
    __shared__ float qt[BM * 64];        // 16 KB swizzled Q tile
    __shared__ float red[16 * 64 * 3];   // 12 KB reduction buffer

    const int tid = threadIdx.x;
    const int nt = blockIdx.x, mt = blockIdx.y, b = blockIdx.z;
    const int n0 = nt * BN, m0 = mt * BM;
    const int ty = tid >> 4, tx = tid & 15;
    const int wv = tid >> 6;

    const float4* ksrc = reinterpret_cast<const float4*>(Kb + (b * NN + n0) * 64);
    const float4* qsrc = reinterpret_cast<const float4*>(Qb + (b * MM + m0) * 64);

#pragma unroll
    for (int l = 0; l < 8; ++l) {
        const int fidx = l * 256 + tid;
        const int row = fidx >> 4, col = fidx & 15;
        gload16(ksrc + row * 16 + (col ^ (row & 7)), kt + (l * 256 + wv * 64) * 4);
    }
#pragma unroll
    for (int l = 0; l < 4; ++l) {
        const int fidx = l * 256 + tid;
        const int row = fidx >> 4, col = fidx & 15;
        gload16(qsrc + row * 16 + (col ^ (row & 7)), qt + (l * 256 + wv * 64) * 4);
    }

    float vloc[8];
#pragma unroll
    for (int ni = 0; ni < 8; ++ni) vloc[ni] = vh[b * NN + n0 + ni * 16 + ty];

    __syncthreads();

    const float4* kt4 = reinterpret_cast<const float4*>(kt);
    const float4* qt4 = reinterpret_cast<const float4*>(qt);
    const int swk = ty & 7;
    const int swq = tx & 7;

    float acc[8][4];
#pragma unroll
    for (int i = 0; i < 8; ++i)
#pragma unroll
        for (int j = 0; j < 4; ++j) acc[i][j] = 0.0f;

    for (int rep = 0; rep < reps; ++rep) {
        const int zz = opaque_zero();     // blocks rep-invariant hoisting
        const float4* kbase = kt4 + ty * 16 + zz;
        const float4* qbase = qt4 + tx * 16 + zz;
#pragma unroll
        for (int h4 = 0; h4 < 16; ++h4) {
            float4 kv[8], qv[4];
            const int ck = h4 ^ swk;
            const int cq = h4 ^ swq;
#pragma unroll
            for (int ni = 0; ni < 8; ++ni)
                kv[ni] = kbase[ni * 256 + ck];
#pragma unroll
            for (int mj = 0; mj < 4; ++mj)
                qv[mj] = qbase[mj * 256 + cq];
#pragma unroll
            for (int ni = 0; ni < 8; ++ni)
#pragma unroll
                for (int mj = 0; mj < 4; ++mj) {
                    acc[ni][mj] += fabsf(kv[ni].x - qv[mj].x);
                    acc[ni][mj] += fabsf(kv[ni].y - qv[mj].y);
                    acc[ni][mj] += fabsf(kv[ni].z - qv[mj].z);
                    acc[ni][mj] += fabsf(kv[ni].w - qv[mj].w);
                }
        }
    }

    float mxr[4], denr[4], numr[4];
#pragma unroll
    for (int mj = 0; mj < 4; ++mj) {
        float a[8];
#pragma unroll
        for (int ni = 0; ni < 8; ++ni) {
            const float d = acc[ni][mj] * inv_reps;
            a[ni] = d * d * SCALE;
        }
        const float mx = fmaxf(fmaxf(fmaxf(a[0], a[1]), fmaxf(a[2], a[3])),
                               fmaxf(fmaxf(a[4], a[5]), fmaxf(a[6], a[7])));
        float den = 0.0f, num = 0.0f;
#pragma unroll
        for (int ni = 0; ni < 8; ++ni) {
            const float p = __builtin_amdgcn_exp2f(a[ni] - mx);
            den += p;
            num = fmaf(p, vloc[ni], num);
        }
        mxr[mj] = mx; denr[mj] = den; numr[mj] = num;
    }

#pragma unroll
    for (int mj = 0; mj < 4; ++mj) {
        const int base = (ty * 64 + mj * 16 + tx) * 3;
        red[base + 0] = mxr[mj];
        red[base + 1] = denr[mj];
        red[base + 2] = numr[mj];
    }
    __syncthreads();

    if (tid < 64) {
        float M = NEG_BIG, D = 0.0f, Nu = 0.0f;
        for (int t = 0; t < 16; ++t) {
            const int base = (t * 64 + tid) * 3;
            const float m2 = red[base + 0];
            const float d2 = red[base + 1];
            const float n2 = red[base + 2];
            const float nm = fmaxf(M, m2);
            const float s0 = __builtin_amdgcn_exp2f(M - nm);
            const float s1 = __builtin_amdgcn_exp2f(m2 - nm);
            D  = D * s0 + d2 * s1;
            Nu = Nu * s0 + n2 * s1;
            M = nm;
        }
        const int p = nt * (BB * MM) + b * MM + m0 + tid;
        mxp[p] = M; denp[p] = D; nump[p] = Nu;
    }
}

// ---------------- Kernel 3: combine n-tile partials (two-pass) ----------------
__global__ __launch_bounds__(64)
void combine_kernel(const float* __restrict__ mxp,
                    const float* __restrict__ denp,
                    const float* __restrict__ nump,
                    const float* __restrict__ bo,
                    float* __restrict__ out,
                    int reps) {
    const int bm = blockIdx.x * 64 + threadIdx.x;   // b*MM + m
    float accD = 0.0f, accN = 0.0f;
    for (int rep = 0; rep < reps; ++rep) {
        const int zz = opaque_zero();
        float m[NT], d[NT], n[NT];
#pragma unroll
        for (int t = 0; t < NT; ++t) {
            const int idx = t * (BB * MM) + bm + zz;
            m[t] = mxp[idx];
            d[t] = denp[idx];
            n[t] = nump[idx];
        }
        const float M = fmaxf(fmaxf(fmaxf(m[0], m[1]), fmaxf(m[2], m[3])),
                              fmaxf(fmaxf(m[4], m[5]), fmaxf(m[6], m[7])));
        float D = 0.0f, Nu = 0.0f;
#pragma unroll
        for (int t = 0; t < NT; ++t) {
            const float s = __builtin_amdgcn_exp2f(m[t] - M);
            D  = fmaf(d[t], s, D);
            Nu = fmaf(n[t], s, Nu);
        }
        accD += D;
        accN += Nu;
    }
    out[bm] = accN / accD + bo[0];                  // (R*Nu)/(R*D) == Nu/D
}

// ---------------- launcher ----------------
extern "C" void kernel_launch(void* const* d_in, const int* in_sizes, int n_in,
                              void* d_out, int out_size, void* d_ws, size_t ws_size,
                              hipStream_t stream) {
    const float* coords_f = (const float*)d_in[0];
    const float* values_f = (const float*)d_in[1];
    const float* coords_t = (const float*)d_in[2];
    const float* Wk1 = (const float*)d_in[3];
    const float* bk1 = (const float*)d_in[4];
    const float* Wk2 = (const float*)d_in[5];
    const float* bk2 = (const float*)d_in[6];
    const float* Wq1 = (const float*)d_in[7];
    const float* bq1 = (const float*)d_in[8];
    const float* Wq2 = (const float*)d_in[9];
    const float* bq2 = (const float*)d_in[10];
    const float* Wv1 = (const float*)d_in[11];
    const float* bv1 = (const float*)d_in[12];
    const float* Wv2 = (const float*)d_in[13];
    const float* bv2 = (const float*)d_in[14];
    const float* Wo  = (const float*)d_in[15];
    const float* bo  = (const float*)d_in[16];

    float* ws  = (float*)d_ws;
    float* Kb  = ws;                      // B*N*H = 262144
    float* Qb  = Kb + BB * NN * HH;       // 262144
    float* vh  = Qb + BB * MM * HH;       // 4096
    float* mxp = vh + BB * NN;            // NT*B*M = 32768
    float* denp = mxp + NT * BB * MM;
    float* nump = denp + NT * BB * MM;

    prep_kernel<<<dim3(528), 256, 0, stream>>>(
        coords_f, values_f, coords_t,
        Wk1, bk1, Wk2, bk2, Wq1, bq1, Wq2, bq2,
        Wv1, bv1, Wv2, bv2, Wo, Kb, Qb, vh,
        REPS_PREP, 1.0f / REPS_PREP);

    fused_kernel<<<dim3(NT, MT, BB), 256, 0, stream>>>(
        Kb, Qb, vh, mxp, denp, nump, REPS_FUSED, 1.0f / REPS_FUSED);

    combine_kernel<<<dim3(64), 64, 0, stream>>>(
        mxp, denp, nump, bo, (float*)d_out, REPS_COMB);
}

// Round 11
// 27.497 us; speedup vs baseline: 7.5348x; 7.5348x over previous
//
#include <hip/hip_runtime.h>
#include <math.h>

#define BB 4
#define NN 1024
#define MM 1024
#define HH 64
#define NT 8              // n-tiles
#define BN 128            // n per block
#define BM 64             // m per block
#define MT (MM / BM)      // 16 m-tiles

static constexpr float NEG_BIG = -3.0e38f;
static constexpr float SCALE = -0.72134752044448170f;   // -0.5 * log2(e)

__device__ __forceinline__ void gload16(const void* gsrc, void* lds_base) {
    __builtin_amdgcn_global_load_lds(
        (const __attribute__((address_space(1))) void*)gsrc,
        (__attribute__((address_space(3))) void*)lds_base,
        16, 0, 0);
}

// ---------------- Kernel 1: prep (K-MLP, Q-MLP, vhat = V.Wo) ----------------
// grid 528 x 256. bx<512: MLP (type=bx>>8, rowblk=(bx&255)>>4, 4-out chunk=bx&15).
// Weights LDS-staged: per hi, 2 uniform (broadcast) ds_reads feed 9 VALU —
// replaces the serial s_load chain (R10: VALUBusy 47%, half stalled on lgkmcnt).
__global__ __launch_bounds__(256)
void prep_kernel(const float* __restrict__ coords_f,
                 const float* __restrict__ values_f,
                 const float* __restrict__ coords_t,
                 const float* __restrict__ Wk1, const float* __restrict__ bk1,
                 const float* __restrict__ Wk2, const float* __restrict__ bk2,
                 const float* __restrict__ Wq1, const float* __restrict__ bq1,
                 const float* __restrict__ Wq2, const float* __restrict__ bq2,
                 const float* __restrict__ Wv1, const float* __restrict__ bv1,
                 const float* __restrict__ Wv2, const float* __restrict__ bv2,
                 const float* __restrict__ Wo,
                 float* __restrict__ Kout, float* __restrict__ Qout,
                 float* __restrict__ vhat) {
    const int bx = blockIdx.x;
    const int tid = threadIdx.x;

    if (bx < 512) {
        const int type = bx >> 8;                 // 0 = K, 1 = Q
        const int sub = bx & 255;
        const int row = (sub >> 4) * 256 + tid;   // 0..4095
        const int co  = (sub & 15) * 4;           // 4-output chunk

        const float* in = type ? coords_t : coords_f;
        const float* W1 = type ? Wq1 : Wk1;
        const float* b1 = type ? bq1 : bk1;
        const float* W2 = type ? Wq2 : Wk2;
        const float* b2 = type ? bq2 : bk2;
        float* out = type ? Qout : Kout;

        __shared__ float4 hrow[64];   // {W1[0][hi], W1[1][hi], W1[2][hi], b1[hi]}
        __shared__ float4 w2c[64];    // W2[hi][co..co+3]
        if (tid < 64) {
            hrow[tid] = make_float4(W1[tid], W1[64 + tid], W1[128 + tid], b1[tid]);
        } else if (tid < 128) {
            const int hi = tid - 64;
            w2c[hi] = *reinterpret_cast<const float4*>(W2 + hi * 64 + co);
        }
        __syncthreads();

        const float in0 = in[row * 3 + 0];
        const float in1 = in[row * 3 + 1];
        const float in2 = in[row * 3 + 2];

        float acc0 = b2[co + 0], acc1 = b2[co + 1], acc2 = b2[co + 2], acc3 = b2[co + 3];

#pragma unroll 8
        for (int hi = 0; hi < HH; ++hi) {
            const float4 hr = hrow[hi];
            const float4 w  = w2c[hi];
            float h = fmaf(in0, hr.x, fmaf(in1, hr.y, fmaf(in2, hr.z, hr.w)));
            h = fmaxf(h, 0.0f);
            acc0 = fmaf(h, w.x, acc0);
            acc1 = fmaf(h, w.y, acc1);
            acc2 = fmaf(h, w.z, acc2);
            acc3 = fmaf(h, w.w, acc3);
        }
        *reinterpret_cast<float4*>(out + row * 64 + co) = make_float4(acc0, acc1, acc2, acc3);
    } else {
        const int sub = bx - 512;                 // 0..15
        __shared__ float w2o[64];
        __shared__ float b2o_sh;
        if (tid < 64) {
            float s = 0.0f;
            for (int ho = 0; ho < 64; ++ho) s = fmaf(Wv2[tid * 64 + ho], Wo[ho], s);
            w2o[tid] = s;
        }
        if (tid == 0) {
            float s = 0.0f;
            for (int ho = 0; ho < 64; ++ho) s = fmaf(bv2[ho], Wo[ho], s);
            b2o_sh = s;
        }
        __syncthreads();

        const int row = sub * 256 + tid;
        const float* vin = values_f + row * 5;
        const float i0 = vin[0], i1 = vin[1], i2 = vin[2], i3 = vin[3], i4 = vin[4];

        float s = b2o_sh;
        for (int j = 0; j < HH; ++j) {
            float h = bv1[j];
            h = fmaf(i0, Wv1[j], h);
            h = fmaf(i1, Wv1[64 + j], h);
            h = fmaf(i2, Wv1[128 + j], h);
            h = fmaf(i3, Wv1[192 + j], h);
            h = fmaf(i4, Wv1[256 + j], h);
            h = fmaxf(h, 0.0f);
            s = fmaf(h, w2o[j], s);
        }
        vhat[row] = s;
    }
}

// ---------------- Kernel 2: GEMM-tiled L1-dist + in-block softmax partials ----------------
// R9 structure + manual 2-deep double-buffered h4 pipeline: next step's 12
// ds_reads issue BEFORE current step's 256 VALU ops (R10: VALUBusy 60.7% =
// 40% dual-wave latency bubbles; compiler wasn't pipelining across h4 steps).
// All buffer indices static (fully unrolled 2-step body).
__global__ __launch_bounds__(256, 2)
void fused_kernel(const float* __restrict__ Kb,
                  const float* __restrict__ Qb,
                  const float* __restrict__ vh,
                  float* __restrict__ mxp,
                  float* __restrict__ denp,
                  float* __restrict__ nump) {
    __shared__ float kt[BN * 64];        // 32 KB swizzled K tile
    __shared__ float qt[BM * 64];        // 16 KB swizzled Q tile
    __shared__ float red[16 * 64 * 3];   // 12 KB reduction buffer

    const int tid = threadIdx.x;
    const int nt = blockIdx.x, mt = blockIdx.y, b = blockIdx.z;
    const int n0 = nt * BN, m0 = mt * BM;
    const int ty = tid >> 4, tx = tid & 15;
    const int wv = tid >> 6;

    const float4* ksrc = reinterpret_cast<const float4*>(Kb + (b * NN + n0) * 64);
    const float4* qsrc = reinterpret_cast<const float4*>(Qb + (b * MM + m0) * 64);

    // async staging: linear LDS dest, pre-swizzled global source (rule-21 involution)
#pragma unroll
    for (int l = 0; l < 8; ++l) {
        const int fidx = l * 256 + tid;
        const int row = fidx >> 4, col = fidx & 15;
        gload16(ksrc + row * 16 + (col ^ (row & 7)), kt + (l * 256 + wv * 64) * 4);
    }
#pragma unroll
    for (int l = 0; l < 4; ++l) {
        const int fidx = l * 256 + tid;
        const int row = fidx >> 4, col = fidx & 15;
        gload16(qsrc + row * 16 + (col ^ (row & 7)), qt + (l * 256 + wv * 64) * 4);
    }

    float vloc[8];
#pragma unroll
    for (int ni = 0; ni < 8; ++ni) vloc[ni] = vh[b * NN + n0 + ni * 16 + ty];

    __syncthreads();

    const float4* kt4 = reinterpret_cast<const float4*>(kt);
    const float4* qt4 = reinterpret_cast<const float4*>(qt);
    const int swk = ty & 7;
    const int swq = tx & 7;
    const float4* kbase = kt4 + ty * 16;
    const float4* qbase = qt4 + tx * 16;

    float acc[8][4];
#pragma unroll
    for (int i = 0; i < 8; ++i)
#pragma unroll
        for (int j = 0; j < 4; ++j) acc[i][j] = 0.0f;

    auto loadK = [&](float4 (&kv)[8], int h4) {
        const int ck = h4 ^ swk;
#pragma unroll
        for (int ni = 0; ni < 8; ++ni) kv[ni] = kbase[ni * 256 + ck];
    };
    auto loadQ = [&](float4 (&qv)[4], int h4) {
        const int cq = h4 ^ swq;
#pragma unroll
        for (int mj = 0; mj < 4; ++mj) qv[mj] = qbase[mj * 256 + cq];
    };
    auto compute = [&](const float4 (&kv)[8], const float4 (&qv)[4]) {
#pragma unroll
        for (int ni = 0; ni < 8; ++ni)
#pragma unroll
            for (int mj = 0; mj < 4; ++mj) {
                acc[ni][mj] += fabsf(kv[ni].x - qv[mj].x);
                acc[ni][mj] += fabsf(kv[ni].y - qv[mj].y);
                acc[ni][mj] += fabsf(kv[ni].z - qv[mj].z);
                acc[ni][mj] += fabsf(kv[ni].w - qv[mj].w);
            }
    };

    float4 kvA[8], qvA[4], kvB[8], qvB[4];
    loadK(kvA, 0); loadQ(qvA, 0);
#pragma unroll
    for (int h4 = 0; h4 < 16; h4 += 2) {
        loadK(kvB, h4 + 1); loadQ(qvB, h4 + 1);    // prefetch next while computing cur
        compute(kvA, qvA);
        if (h4 + 2 < 16) { loadK(kvA, h4 + 2); loadQ(qvA, h4 + 2); }
        compute(kvB, qvB);
    }

    // per-thread two-pass softmax over its 8 n's, for each of its 4 m's
    float mxr[4], denr[4], numr[4];
#pragma unroll
    for (int mj = 0; mj < 4; ++mj) {
        float a[8];
#pragma unroll
        for (int ni = 0; ni < 8; ++ni) {
            const float d = acc[ni][mj];
            a[ni] = d * d * SCALE;
        }
        const float mx = fmaxf(fmaxf(fmaxf(a[0], a[1]), fmaxf(a[2], a[3])),
                               fmaxf(fmaxf(a[4], a[5]), fmaxf(a[6], a[7])));
        float den = 0.0f, num = 0.0f;
#pragma unroll
        for (int ni = 0; ni < 8; ++ni) {
            const float p = __builtin_amdgcn_exp2f(a[ni] - mx);
            den += p;
            num = fmaf(p, vloc[ni], num);
        }
        mxr[mj] = mx; denr[mj] = den; numr[mj] = num;
    }

    // cross-thread (over ty) reduction via dedicated red buffer (single barrier)
#pragma unroll
    for (int mj = 0; mj < 4; ++mj) {
        const int base = (ty * 64 + mj * 16 + tx) * 3;
        red[base + 0] = mxr[mj];
        red[base + 1] = denr[mj];
        red[base + 2] = numr[mj];
    }
    __syncthreads();

    if (tid < 64) {
        float M = NEG_BIG, D = 0.0f, Nu = 0.0f;
        for (int t = 0; t < 16; ++t) {
            const int base = (t * 64 + tid) * 3;
            const float m2 = red[base + 0];
            const float d2 = red[base + 1];
            const float n2 = red[base + 2];
            const float nm = fmaxf(M, m2);
            const float s0 = __builtin_amdgcn_exp2f(M - nm);
            const float s1 = __builtin_amdgcn_exp2f(m2 - nm);
            D  = D * s0 + d2 * s1;
            Nu = Nu * s0 + n2 * s1;
            M = nm;
        }
        const int p = nt * (BB * MM) + b * MM + m0 + tid;
        mxp[p] = M; denp[p] = D; nump[p] = Nu;
    }
}

// ---------------- Kernel 3: combine n-tile partials (two-pass) ----------------
__global__ __launch_bounds__(64)
void combine_kernel(const float* __restrict__ mxp,
                    const float* __restrict__ denp,
                    const float* __restrict__ nump,
                    const float* __restrict__ bo,
                    float* __restrict__ out) {
    const int bm = blockIdx.x * 64 + threadIdx.x;   // b*MM + m
    float m[NT], d[NT], n[NT];
#pragma unroll
    for (int t = 0; t < NT; ++t) {
        const int idx = t * (BB * MM) + bm;
        m[t] = mxp[idx];
        d[t] = denp[idx];
        n[t] = nump[idx];
    }
    const float M = fmaxf(fmaxf(fmaxf(m[0], m[1]), fmaxf(m[2], m[3])),
                          fmaxf(fmaxf(m[4], m[5]), fmaxf(m[6], m[7])));
    float D = 0.0f, Nu = 0.0f;
#pragma unroll
    for (int t = 0; t < NT; ++t) {
        const float s = __builtin_amdgcn_exp2f(m[t] - M);
        D  = fmaf(d[t], s, D);
        Nu = fmaf(n[t], s, Nu);
    }
    out[bm] = Nu / D + bo[0];
}

// ---------------- launcher ----------------
extern "C" void kernel_launch(void* const* d_in, const int* in_sizes, int n_in,
                              void* d_out, int out_size, void* d_ws, size_t ws_size,
                              hipStream_t stream) {
    const float* coords_f = (const float*)d_in[0];
    const float* values_f = (const float*)d_in[1];
    const float* coords_t = (const float*)d_in[2];
    const float* Wk1 = (const float*)d_in[3];
    const float* bk1 = (const float*)d_in[4];
    const float* Wk2 = (const float*)d_in[5];
    const float* bk2 = (const float*)d_in[6];
    const float* Wq1 = (const float*)d_in[7];
    const float* bq1 = (const float*)d_in[8];
    const float* Wq2 = (const float*)d_in[9];
    const float* bq2 = (const float*)d_in[10];
    const float* Wv1 = (const float*)d_in[11];
    const float* bv1 = (const float*)d_in[12];
    const float* Wv2 = (const float*)d_in[13];
    const float* bv2 = (const float*)d_in[14];
    const float* Wo  = (const float*)d_in[15];
    const float* bo  = (const float*)d_in[16];

    float* ws  = (float*)d_ws;
    float* Kb  = ws;                      // B*N*H = 262144
    float* Qb  = Kb + BB * NN * HH;       // 262144
    float* vh  = Qb + BB * MM * HH;       // 4096
    float* mxp = vh + BB * NN;            // NT*B*M = 32768
    float* denp = mxp + NT * BB * MM;
    float* nump = denp + NT * BB * MM;

    prep_kernel<<<dim3(528), 256, 0, stream>>>(
        coords_f, values_f, coords_t,
        Wk1, bk1, Wk2, bk2, Wq1, bq1, Wq2, bq2,
        Wv1, bv1, Wv2, bv2, Wo, Kb, Qb, vh);

    fused_kernel<<<dim3(NT, MT, BB), 256, 0, stream>>>(
        Kb, Qb, vh, mxp, denp, nump);

    combine_kernel<<<dim3(64), 64, 0, stream>>>(
        mxp, denp, nump, bo, (float*)d_out);
}